// Round 6
// baseline (293.785 us; speedup 1.0000x reference)
//
#include <hip/hip_runtime.h>
#include <hip/hip_bf16.h>

typedef __bf16 bf16;
typedef __attribute__((ext_vector_type(4)))  __bf16 bf16x4;
typedef __attribute__((ext_vector_type(8)))  __bf16 bf16x8;
typedef __attribute__((ext_vector_type(16))) float  f32x16;

#define B_   512
#define NC_  512
#define K_   4
#define S_   8
#define H_   128
#define D_   64
#define XROW (NC_ * K_)

// pi: swap bits 2,3 of within-32 index (involution). Hidden dims stored
// physically permuted so the 32x32 MFMA C/D register layout of layer k IS
// the B-fragment layout of layer k+1 (r3-verified algebra).
static __device__ __forceinline__ int swap23(int v) {
    return (v & ~12) | ((v & 4) << 1) | ((v & 8) >> 1);
}

__global__ __launch_bounds__(256, 2)
void jt_mlp_kernel(const int*   __restrict__ x,
                   const float* __restrict__ W1g, const float* __restrict__ b1g,
                   const float* __restrict__ W2g, const float* __restrict__ b2g,
                   const float* __restrict__ W3g, const float* __restrict__ b3g,
                   float* __restrict__ out)
{
    // Swizzled bf16 weight stores: element (p,k) lives at
    //   row p * rowlen + ((k>>3) ^ (p & chmask)) * 8 + (k&7)
    // -> every wave64 b128 fragment read is bank-uniform (conflict-free).
    __shared__ __align__(16) bf16 SW1[128 * 64];    // 16 KB  W1^T (b1 folded)
    __shared__ __align__(16) bf16 SW2[128 * 128];   // 32 KB  W2^T
    __shared__ __align__(16) bf16 SW3[8 * 128];     // 2 KB   W3^T

    const int tid  = threadIdx.x;
    const int lane = tid & 63;
    const int w    = tid >> 6;      // wave 0..3: items [w*128, w*128+128)
    const int l31  = lane & 31;
    const int lhi  = lane >> 5;
    const int kk   = l31 & 3;
    const int n    = blockIdx.x;    // clique

    const float* W1p = W1g + (size_t)n * (D_ * H_);
    const float* W2p = W2g + (size_t)n * (H_ * H_);
    const float* W3p = W3g + (size_t)n * (H_ * S_);
    const float* b1p = b1g + n * H_;
    const float* b2p = b2g + n * H_;
    const float* b3p = b3g + n * S_;

    const int p31 = swap23(l31);
    const bf16 one = (bf16)1.0f, zero = (bf16)0.0f;

    // ================= stage weights into LDS (coalesced float4) =================
    // W1: physical row p holds W1[k][pi(p)]; k<8 rows carry +b1 (parent-var-0
    // one-hot fires it exactly once; root n==0 zeroes k<32 except the bias).
    {
        const int c0 = (tid & 31) * 4;
        const int k0 = (tid >> 5) * 8;          // 0..56
        float rows[8][4];
#pragma unroll
        for (int i = 0; i < 8; ++i) {
            float4 t4 = *(const float4*)(W1p + (k0 + i) * H_ + c0);
            if (n == 0 && k0 < 32) t4 = make_float4(0.f, 0.f, 0.f, 0.f);
            rows[i][0] = t4.x; rows[i][1] = t4.y; rows[i][2] = t4.z; rows[i][3] = t4.w;
        }
        if (k0 == 0) {
            const float4 bb = *(const float4*)(b1p + c0);
#pragma unroll
            for (int i = 0; i < 8; ++i) {
                rows[i][0] += bb.x; rows[i][1] += bb.y;
                rows[i][2] += bb.z; rows[i][3] += bb.w;
            }
        }
#pragma unroll
        for (int j2 = 0; j2 < 4; ++j2) {
            const int c = c0 + j2;
            const int p = (c & ~31) | swap23(c & 31);
            const int ch = (k0 >> 3) ^ (p & 7);
            bf16x4 lo, hi;
#pragma unroll
            for (int i = 0; i < 4; ++i) {
                lo[i] = (bf16)rows[i][j2];
                hi[i] = (bf16)rows[4 + i][j2];
            }
            *(bf16x4*)&SW1[p * 64 + ch * 8 + 0] = lo;
            *(bf16x4*)&SW1[p * 64 + ch * 8 + 4] = hi;
        }
    }
    // W2
    {
        const int c0 = (tid & 31) * 4;
        const int kbase = (tid >> 5) * 16;      // 0..112
#pragma unroll
        for (int hh = 0; hh < 2; ++hh) {
            const int k0 = kbase + hh * 8;
            float rows[8][4];
#pragma unroll
            for (int i = 0; i < 8; ++i) {
                const float4 t4 = *(const float4*)(W2p + (k0 + i) * H_ + c0);
                rows[i][0] = t4.x; rows[i][1] = t4.y; rows[i][2] = t4.z; rows[i][3] = t4.w;
            }
#pragma unroll
            for (int j2 = 0; j2 < 4; ++j2) {
                const int c = c0 + j2;
                const int p = (c & ~31) | swap23(c & 31);
                const int ch = (k0 >> 3) ^ (p & 15);
                bf16x4 lo, hi;
#pragma unroll
                for (int i = 0; i < 4; ++i) {
                    lo[i] = (bf16)rows[i][j2];
                    hi[i] = (bf16)rows[4 + i][j2];
                }
                *(bf16x4*)&SW2[p * 128 + ch * 8 + 0] = lo;
                *(bf16x4*)&SW2[p * 128 + ch * 8 + 4] = hi;
            }
        }
    }
    // W3^T[s][k] (states not permuted; k logical)
    if (tid < 128) {
        const int s = tid >> 4, kc = tid & 15, k0 = kc * 8;
        float vv[8];
#pragma unroll
        for (int i = 0; i < 8; ++i) vv[i] = W3p[(k0 + i) * S_ + s];
        const int ch = kc ^ s;
        bf16x4 lo, hi;
#pragma unroll
        for (int i = 0; i < 4; ++i) { lo[i] = (bf16)vv[i]; hi[i] = (bf16)vv[4 + i]; }
        *(bf16x4*)&SW3[s * 128 + ch * 8 + 0] = lo;
        *(bf16x4*)&SW3[s * 128 + ch * 8 + 4] = hi;
    }

    // ---- small per-wave invariants (global loads, independent of staging) ----
    bf16x8 w2b[4];          // b2 as k=0-slot bias fragments (fired by onef)
#pragma unroll
    for (int a = 0; a < 4; ++a) {
#pragma unroll
        for (int j = 0; j < 8; ++j) w2b[a][j] = zero;
        w2b[a][0] = lhi ? zero : (bf16)b2p[32 * a + p31];
    }
    bf16x8 onef;
#pragma unroll
    for (int j = 0; j < 8; ++j) onef[j] = zero;
    onef[0] = lhi ? zero : one;
    const float4 b3q = *(const float4*)(b3p + 4 * lhi);   // states 4lhi..4lhi+3

    f32x16 zf;
#pragma unroll
    for (int i = 0; i < 16; ++i) zf[i] = 0.f;

    __syncthreads();   // the ONLY barrier — weights visible; waves free-run now

    // ---- register-resident half of W2 (kt=0..3, all 4 m-blocks; const idx) ----
    bf16x8 w2r[4][4];
#pragma unroll
    for (int a = 0; a < 4; ++a)
#pragma unroll
        for (int t = 0; t < 4; ++t) {
            const int p = 32 * a + l31;
            w2r[a][t] = *(const bf16x8*)&SW2[p * 128 + (((t << 1) + lhi) ^ (l31 & 15)) * 8];
        }

    // -------- x prefetch --------
    const int itbase = w * 128 + (l31 >> 2);
    int4 xo_c, xp_c;
    {
        const int* xb = x + (size_t)itbase * XROW + n * K_;
        xo_c = *(const int4*)xb;
        xp_c = (n > 0) ? *(const int4*)(xb - K_) : make_int4(0, 0, 0, 0);
    }

#pragma unroll 1
    for (int c = 0; c < 16; ++c) {
        const int item = itbase + c * 8;
        const int4 xo = xo_c, xp = xp_c;
        if (c < 15) {
            const int* xb = x + (size_t)(item + 8) * XROW + n * K_;
            xo_c = *(const int4*)xb;
            xp_c = (n > 0) ? *(const int4*)(xb - K_) : make_int4(0, 0, 0, 0);
        }

        // ---- one-hot B-frags from x (r3-verified) ----
        int sel[4];
        sel[0] = (n > 0) ? (lhi ? xp.y : xp.x) : (lhi ? -1 : 0);
        sel[1] = (n > 0) ? (lhi ? xp.w : xp.z) : -1;
        sel[2] = (kk > (lhi ? 1 : 0)) ? (lhi ? xo.y : xo.x) : -1;
        sel[3] = (kk > (lhi ? 3 : 2)) ? (lhi ? xo.w : xo.z) : -1;
        bf16x8 bf1[4];
#pragma unroll
        for (int kt = 0; kt < 4; ++kt)
#pragma unroll
            for (int j = 0; j < 8; ++j)
                bf1[kt][j] = (sel[kt] == j) ? one : zero;

        // ---- layer 1: weights streamed from LDS (conflict-free b128) ----
        f32x16 A[4];
#pragma unroll
        for (int a = 0; a < 4; ++a) A[a] = zf;
#pragma unroll
        for (int kt = 0; kt < 4; ++kt)
#pragma unroll
            for (int a = 0; a < 4; ++a) {
                const bf16x8 f = *(const bf16x8*)
                    &SW1[(32 * a + l31) * 64 + (((kt << 1) + lhi) ^ (l31 & 7)) * 8];
                A[a] = __builtin_amdgcn_mfma_f32_32x32x16_bf16(f, bf1[kt], A[a], 0, 0, 0);
            }

        // ---- extract h1 B-frags in-register (chained layout), A dies ----
        bf16x8 hf[8];
#pragma unroll
        for (int t = 0; t < 8; ++t)
#pragma unroll
            for (int j = 0; j < 8; ++j)
                hf[t][j] = (bf16)fmaxf(A[t >> 1][8 * (t & 1) + j], 0.f);

        // ---- layer 2: kt=0..3 from registers, kt=4..7 from LDS ----
        f32x16 Cc[4];
#pragma unroll
        for (int a = 0; a < 4; ++a) Cc[a] = zf;
#pragma unroll
        for (int t = 0; t < 4; ++t)
#pragma unroll
            for (int a = 0; a < 4; ++a)
                Cc[a] = __builtin_amdgcn_mfma_f32_32x32x16_bf16(w2r[a][t], hf[t], Cc[a], 0, 0, 0);
#pragma unroll
        for (int t = 0; t < 4; ++t)
#pragma unroll
            for (int a = 0; a < 4; ++a) {
                const int p = 32 * a + l31;
                const bf16x8 f = *(const bf16x8*)
                    &SW2[p * 128 + (((8 + (t << 1)) + lhi) ^ (l31 & 15)) * 8];
                Cc[a] = __builtin_amdgcn_mfma_f32_32x32x16_bf16(f, hf[4 + t], Cc[a], 0, 0, 0);
            }
#pragma unroll
        for (int a = 0; a < 4; ++a)
            Cc[a] = __builtin_amdgcn_mfma_f32_32x32x16_bf16(w2b[a], onef, Cc[a], 0, 0, 0);

        // ---- extract h2 B-frags, Cc dies ----
        bf16x8 hg[8];
#pragma unroll
        for (int t = 0; t < 8; ++t)
#pragma unroll
            for (int j = 0; j < 8; ++j)
                hg[t][j] = (bf16)fmaxf(Cc[t >> 1][8 * (t & 1) + j], 0.f);

        // ---- layer 3: full k in-wave; rows m=0..7 = states ----
        f32x16 L = zf;
#pragma unroll
        for (int t = 0; t < 8; ++t) {
            const int s2 = l31 & 7;   // lanes 8..31 duplicate rows (outputs unused)
            const bf16x8 f = *(const bf16x8*)
                &SW3[s2 * 128 + (((t << 1) + lhi) ^ s2) * 8];
            L = __builtin_amdgcn_mfma_f32_32x32x16_bf16(f, hg[t], L, 0, 0, 0);
        }
        // D: col = l31 = batch row; regs 0..3 = states 4*lhi..4*lhi+3

        // ---- register log-softmax + gather + sum over K (r3-verified) ----
        const float Ls0 = L[0] + b3q.x, Ls1 = L[1] + b3q.y;
        const float Ls2 = L[2] + b3q.z, Ls3 = L[3] + b3q.w;
        float m4 = fmaxf(fmaxf(Ls0, Ls1), fmaxf(Ls2, Ls3));
        const float mm = fmaxf(m4, __shfl_xor(m4, 32));
        float e = __expf(Ls0 - mm) + __expf(Ls1 - mm) +
                  __expf(Ls2 - mm) + __expf(Ls3 - mm);
        const float ssum = e + __shfl_xor(e, 32);
        const int xs = (kk & 2) ? ((kk & 1) ? xo.w : xo.z)
                                : ((kk & 1) ? xo.y : xo.x);
        const float own = (xs & 2) ? ((xs & 1) ? Ls3 : Ls2)
                                   : ((xs & 1) ? Ls1 : Ls0);
        const float oth = __shfl_xor(own, 32);
        const float obs = ((xs >> 2) == lhi) ? own : oth;
        float lp = obs - mm - __logf(ssum);
        lp += __shfl_xor(lp, 1);
        lp += __shfl_xor(lp, 2);
        if (lhi == 0 && kk == 0)
            out[(size_t)item * NC_ + n] = lp;
    }
}

extern "C" void kernel_launch(void* const* d_in, const int* in_sizes, int n_in,
                              void* d_out, int out_size, void* d_ws, size_t ws_size,
                              hipStream_t stream) {
    const int*   x  = (const int*)d_in[0];
    const float* W1 = (const float*)d_in[1];
    const float* b1 = (const float*)d_in[2];
    const float* W2 = (const float*)d_in[3];
    const float* b2 = (const float*)d_in[4];
    const float* W3 = (const float*)d_in[5];
    const float* b3 = (const float*)d_in[6];
    float* out = (float*)d_out;
    jt_mlp_kernel<<<dim3(NC_), 256, 0, stream>>>(x, W1, b1, W2, b2, W3, b3, out);
}

// Round 7
// 228.487 us; speedup vs baseline: 1.2858x; 1.2858x over previous
//
#include <hip/hip_runtime.h>
#include <hip/hip_bf16.h>

typedef __bf16 bf16;
typedef __attribute__((ext_vector_type(8)))  __bf16 bf16x8;
typedef __attribute__((ext_vector_type(16))) float  f32x16;

#define B_   512
#define NC_  512
#define K_   4
#define S_   8
#define H_   128
#define D_   64
#define XROW (NC_ * K_)

#define SEGS 2
#define ITEMS_PER_BLOCK (B_ / SEGS)   // 256
#define NITER 16                      // 256 items / (2 pairs * 8 items/iter)

// pi: swap bits 2,3 of within-32 index. Hidden dims stored physically permuted
// so the 32x32 MFMA C/D register layout of layer k IS the B-frag of layer k+1.
static __device__ __forceinline__ int swap23(int v) {
    return (v & ~12) | ((v & 4) << 1) | ((v & 8) >> 1);
}

// launch_bounds(256,1): allocator budget 256 VGPRs. r5/r6 proved (256,2)
// hard-caps VGPR_Count at 128 -> spill (r5: 9MB scratch, r6: 77MB). Demand
// here is ~160-200 regs; at 256 budget there is no spill and we still get
// 2 blocks/CU (LDS 36KB, VGPR 2 waves/SIMD) matching r5's MEASURED 1.6.
__global__ __launch_bounds__(256, 1)
void jt_mlp_kernel(const int*   __restrict__ x,
                   const float* __restrict__ W1g, const float* __restrict__ b1g,
                   const float* __restrict__ W2g, const float* __restrict__ b2g,
                   const float* __restrict__ W3g, const float* __restrict__ b3g,
                   float* __restrict__ out)
{
    // exchange buffers: [buf][pair][half][frag][lane][8 bf16]  (lane-contiguous 16B)
    __shared__ __align__(16) bf16  HX[2][2][2][4][64][8];   // 32 KB
    __shared__ __align__(16) float LX[2][2][64][4];         // 4 KB (h=1 writes, h=0 reads)

    const int tid  = threadIdx.x;
    const int lane = tid & 63;
    const int w    = tid >> 6;      // 0..3
    const int pair = w >> 1;        // 0,1
    const int h    = w & 1;         // H-half owned by this wave
    const int l31  = lane & 31;
    const int lhi  = lane >> 5;
    const int kk   = l31 & 3;       // within-item variable position

    const int n    = blockIdx.x >> 1;   // clique
    const int seg  = blockIdx.x & 1;

    const float* W1p = W1g + (size_t)n * (D_ * H_);
    const float* W2p = W2g + (size_t)n * (H_ * H_);
    const float* W3p = W3g + (size_t)n * (H_ * S_);
    const float* b1p = b1g + n * H_;
    const float* b2p = b2g + n * H_;
    const float* b3p = b3g + n * S_;

    const int p31 = swap23(l31);
    const bf16 one = (bf16)1.0f, zero = (bf16)0.0f;

    // -------- register-resident weight fragments (this wave's H-half) --------
    // Every register-array subscript is a compile-time constant after
    // unrolling; runtime `h` appears ONLY in address arithmetic (r4 lesson).
    // 32x32x16 A-layout: lane holds A[m=lane&31][k=(lane>>5)*8+j]
    bf16x8 w1f[2][4];
#pragma unroll
    for (int a = 0; a < 2; ++a) {
        const int pc = 32 * (2 * h + a) + p31;
        const float bb = b1p[pc];
#pragma unroll
        for (int kt = 0; kt < 4; ++kt)
#pragma unroll
            for (int j = 0; j < 8; ++j) {
                const int k = kt * 16 + lhi * 8 + j;
                float v = W1p[k * H_ + pc];
                if (kt == 0) {   // parent-var-0 block carries b1 (root: synthetic state-0)
                    const float vb = (n > 0 ? v : 0.f) + bb;
                    v = lhi ? v : vb;
                }
                w1f[a][kt][j] = (bf16)v;
            }
    }
    // W2 split: own k-quarters (kt = 4h+t) and partner k-quarters (kt = 4(1-h)+t),
    // both indexed by constant t in the main loop.
    bf16x8 w2f_o[2][4], w2f_p[2][4], w2b[2];
#pragma unroll
    for (int a = 0; a < 2; ++a) {
        const int pc = 32 * (2 * h + a) + p31;
#pragma unroll
        for (int t = 0; t < 4; ++t)
#pragma unroll
            for (int j = 0; j < 8; ++j) {
                const int ko = (4 * h + t) * 16 + lhi * 8 + j;
                const int kp = (4 * (1 - h) + t) * 16 + lhi * 8 + j;
                w2f_o[a][t][j] = (bf16)W2p[ko * H_ + pc];
                w2f_p[a][t][j] = (bf16)W2p[kp * H_ + pc];
            }
#pragma unroll
        for (int j = 0; j < 8; ++j) w2b[a][j] = zero;
        w2b[a][0] = lhi ? zero : (bf16)b2p[pc];
    }
    // L3 over this wave's k-half: frag t covers k = 64h + 16t + 8lhi + j
    bf16x8 w3f[4];
#pragma unroll
    for (int t = 0; t < 4; ++t)
#pragma unroll
        for (int j = 0; j < 8; ++j)
            w3f[t][j] = (l31 < S_) ? (bf16)W3p[(64 * h + 16 * t + lhi * 8 + j) * S_ + l31]
                                   : zero;
    bf16x8 onef;
#pragma unroll
    for (int j = 0; j < 8; ++j) onef[j] = zero;
    onef[0] = lhi ? zero : one;

    const float4 b3q = *(const float4*)(b3p + 4 * lhi);   // states 4lhi..4lhi+3

    f32x16 zf;
#pragma unroll
    for (int i = 0; i < 16; ++i) zf[i] = 0.f;

    // -------- x prefetch --------
    const int itbase = seg * ITEMS_PER_BLOCK + pair * 128 + (l31 >> 2);
    int4 xo_c, xp_c;
    {
        const int* xb = x + (size_t)itbase * XROW + n * K_;
        xo_c = *(const int4*)xb;
        xp_c = (n > 0) ? *(const int4*)(xb - K_) : make_int4(0, 0, 0, 0);
    }

#pragma unroll 1
    for (int c = 0; c < NITER; ++c) {
        const int buf  = c & 1;
        const int item = itbase + c * 8;
        const int4 xo = xo_c, xp = xp_c;
        if (c < NITER - 1) {
            const int* xb = x + (size_t)(item + 8) * XROW + n * K_;
            xo_c = *(const int4*)xb;
            xp_c = (n > 0) ? *(const int4*)(xb - K_) : make_int4(0, 0, 0, 0);
        }

        // ---- one-hot B-frags from x ----
        int sel[4];
        sel[0] = (n > 0) ? (lhi ? xp.y : xp.x) : (lhi ? -1 : 0);
        sel[1] = (n > 0) ? (lhi ? xp.w : xp.z) : -1;
        sel[2] = (kk > (lhi ? 1 : 0)) ? (lhi ? xo.y : xo.x) : -1;
        sel[3] = (kk > (lhi ? 3 : 2)) ? (lhi ? xo.w : xo.z) : -1;
        bf16x8 bf1[4];
#pragma unroll
        for (int kt = 0; kt < 4; ++kt)
#pragma unroll
            for (int j = 0; j < 8; ++j)
                bf1[kt][j] = (sel[kt] == j) ? one : zero;

        // ---- layer 1 (own H-half) ----
        f32x16 Aa0 = zf, Aa1 = zf;
#pragma unroll
        for (int kt = 0; kt < 4; ++kt) {
            Aa0 = __builtin_amdgcn_mfma_f32_32x32x16_bf16(w1f[0][kt], bf1[kt], Aa0, 0, 0, 0);
            Aa1 = __builtin_amdgcn_mfma_f32_32x32x16_bf16(w1f[1][kt], bf1[kt], Aa1, 0, 0, 0);
        }

        // ---- extract own h1 frags (chained layout), publish to partner ----
        bf16x8 hfo[4];
#pragma unroll
        for (int t = 0; t < 4; ++t) {
            const f32x16& S = (t < 2) ? Aa0 : Aa1;
#pragma unroll
            for (int j = 0; j < 8; ++j)
                hfo[t][j] = (bf16)fmaxf(S[8 * (t & 1) + j], 0.f);
            *(bf16x8*)&HX[buf][pair][h][t][lane][0] = hfo[t];
        }
        __syncthreads();

        // ---- layer 2: own 4 kt-frags + partner's 4 from LDS (const indices) ----
        f32x16 Cc0 = zf, Cc1 = zf;
#pragma unroll
        for (int t = 0; t < 4; ++t) {
            Cc0 = __builtin_amdgcn_mfma_f32_32x32x16_bf16(w2f_o[0][t], hfo[t], Cc0, 0, 0, 0);
            Cc1 = __builtin_amdgcn_mfma_f32_32x32x16_bf16(w2f_o[1][t], hfo[t], Cc1, 0, 0, 0);
        }
#pragma unroll
        for (int t = 0; t < 4; ++t) {
            bf16x8 hp = *(const bf16x8*)&HX[buf][pair][1 - h][t][lane][0];
            Cc0 = __builtin_amdgcn_mfma_f32_32x32x16_bf16(w2f_p[0][t], hp, Cc0, 0, 0, 0);
            Cc1 = __builtin_amdgcn_mfma_f32_32x32x16_bf16(w2f_p[1][t], hp, Cc1, 0, 0, 0);
        }
        Cc0 = __builtin_amdgcn_mfma_f32_32x32x16_bf16(w2b[0], onef, Cc0, 0, 0, 0);
        Cc1 = __builtin_amdgcn_mfma_f32_32x32x16_bf16(w2b[1], onef, Cc1, 0, 0, 0);

        // ---- layer 3 partial over own k-half ----
        f32x16 L = zf;
#pragma unroll
        for (int t = 0; t < 4; ++t) {
            bf16x8 hf;
            const f32x16& S = (t < 2) ? Cc0 : Cc1;
#pragma unroll
            for (int j = 0; j < 8; ++j)
                hf[j] = (bf16)fmaxf(S[8 * (t & 1) + j], 0.f);
            L = __builtin_amdgcn_mfma_f32_32x32x16_bf16(w3f[t], hf, L, 0, 0, 0);
        }

        // ---- sum partials across the pair; epilogue on h==0 wave ----
        if (h == 1)
            *(float4*)&LX[buf][pair][lane][0] = make_float4(L[0], L[1], L[2], L[3]);
        __syncthreads();
        if (h == 0) {
            const float4 Lp = *(const float4*)&LX[buf][pair][lane][0];
            float Ls0 = L[0] + Lp.x + b3q.x;
            float Ls1 = L[1] + Lp.y + b3q.y;
            float Ls2 = L[2] + Lp.z + b3q.z;
            float Ls3 = L[3] + Lp.w + b3q.w;

            float m4 = fmaxf(fmaxf(Ls0, Ls1), fmaxf(Ls2, Ls3));
            const float mm = fmaxf(m4, __shfl_xor(m4, 32));
            float e = __expf(Ls0 - mm) + __expf(Ls1 - mm) +
                      __expf(Ls2 - mm) + __expf(Ls3 - mm);
            const float ssum = e + __shfl_xor(e, 32);

            const int xs = (kk & 2) ? ((kk & 1) ? xo.w : xo.z)
                                    : ((kk & 1) ? xo.y : xo.x);
            const float own = (xs & 2) ? ((xs & 1) ? Ls3 : Ls2)
                                       : ((xs & 1) ? Ls1 : Ls0);
            const float oth = __shfl_xor(own, 32);
            const float obs = ((xs >> 2) == lhi) ? own : oth;
            float lp = obs - mm - __logf(ssum);
            lp += __shfl_xor(lp, 1);
            lp += __shfl_xor(lp, 2);
            if (lhi == 0 && kk == 0)
                out[(size_t)item * NC_ + n] = lp;
        }
    }
}

extern "C" void kernel_launch(void* const* d_in, const int* in_sizes, int n_in,
                              void* d_out, int out_size, void* d_ws, size_t ws_size,
                              hipStream_t stream) {
    const int*   x  = (const int*)d_in[0];
    const float* W1 = (const float*)d_in[1];
    const float* b1 = (const float*)d_in[2];
    const float* W2 = (const float*)d_in[3];
    const float* b2 = (const float*)d_in[4];
    const float* W3 = (const float*)d_in[5];
    const float* b3 = (const float*)d_in[6];
    float* out = (float*)d_out;
    jt_mlp_kernel<<<dim3(NC_ * SEGS), 256, 0, stream>>>(x, W1, b1, W2, b2, W3, b3, out);
}